// Round 4
// baseline (849.178 us; speedup 1.0000x reference)
//
#include <hip/hip_runtime.h>

#define T_ 2048
#define C_ 64
#define LSTRIDE 148       // padded LDS stride (592 B = 37*16B): chain reads 2-way max
#define NQ_ 76            // matrices per block: p = t0 .. t0+75

// ------------------------------------------------------------------
// Quad-lane DPP broadcast: all 4 lanes of a quad get lane Q's value.
// ------------------------------------------------------------------
template <int Q>
__device__ __forceinline__ float qb(float v) {
  return __int_as_float(
      __builtin_amdgcn_mov_dpp(__float_as_int(v), Q * 0x55, 0xf, 0xf, true));
}

// C(3x12, own rows) = A(3x12, own rows) * B(12x12, quad-distributed rows)
__device__ __forceinline__ void qmm(const float a[3][12], const float b[3][12],
                                    float c[3][12]) {
#pragma unroll
  for (int i = 0; i < 3; ++i)
#pragma unroll
    for (int j = 0; j < 12; ++j) c[i][j] = 0.f;
#define QMM_K(OWNER, E)                                                  \
  {                                                                      \
    float bk[12];                                                        \
    _Pragma("unroll")                                                    \
    for (int j = 0; j < 12; ++j) bk[j] = qb<OWNER>(b[E][j]);             \
    _Pragma("unroll")                                                    \
    for (int i = 0; i < 3; ++i) {                                        \
      const float av = a[i][3 * OWNER + E];                              \
      _Pragma("unroll")                                                  \
      for (int j = 0; j < 12; ++j) c[i][j] = fmaf(av, bk[j], c[i][j]);   \
    }                                                                    \
  }
  QMM_K(0, 0) QMM_K(0, 1) QMM_K(0, 2)
  QMM_K(1, 0) QMM_K(1, 1) QMM_K(1, 2)
  QMM_K(2, 0) QMM_K(2, 1) QMM_K(2, 2)
  QMM_K(3, 0) QMM_K(3, 1) QMM_K(3, 2)
#undef QMM_K
}

// C(3x12, own rows) = A(3x12, own rows) * B(12x12 in LDS, rows contiguous)
// Quad-uniform addresses -> LDS broadcast.
__device__ __forceinline__ void matmul_rows(const float a[3][12],
                                            const float* lb, float c[3][12]) {
#pragma unroll
  for (int i = 0; i < 3; ++i)
#pragma unroll
    for (int j = 0; j < 12; ++j) c[i][j] = 0.f;
#pragma unroll
  for (int k = 0; k < 12; ++k) {
    float4 b0 = *(const float4*)(lb + k * 12 + 0);
    float4 b1 = *(const float4*)(lb + k * 12 + 4);
    float4 b2 = *(const float4*)(lb + k * 12 + 8);
#pragma unroll
    for (int i = 0; i < 3; ++i) {
      const float a_ = a[i][k];
      c[i][0] += a_ * b0.x;  c[i][1] += a_ * b0.y;  c[i][2]  += a_ * b0.z;  c[i][3]  += a_ * b0.w;
      c[i][4] += a_ * b1.x;  c[i][5] += a_ * b1.y;  c[i][6]  += a_ * b1.z;  c[i][7]  += a_ * b1.w;
      c[i][8] += a_ * b2.x;  c[i][9] += a_ * b2.y;  c[i][10] += a_ * b2.z;  c[i][11] += a_ * b2.w;
    }
  }
}

// ------------------------------------------------------------------
// Fully fused: per block = (b, t0..t0+63). Build 76 scaled M's in regs
// (dx in regs via quad-DPP, ask broadcast from LDS), expm in regs
// (PS-6 Taylor + 5 squarings), E -> LDS (union with ask), chain + output.
// 320 threads = 5 waves = 80 quads (76 used for expm, 64 for chain).
// ------------------------------------------------------------------
__global__ __launch_bounds__(320, 3) void fused_kernel(const float* __restrict__ x,
                                                       const float* __restrict__ A,
                                                       float* __restrict__ out) {
  __shared__ float smem[NQ_ * LSTRIDE];   // 44992 B; ask (9216 floats) unions with eb
  const int b = blockIdx.y;
  const int t0 = blockIdx.x * 64;
  const int tid = threadIdx.x;
  const int q = tid >> 2;     // quad 0..79
  const int eg = tid & 3;     // lane in quad: owns rows 3eg..3eg+2

  // ---- stage scaled skew-symmetrized A into LDS ----
  float (*ask)[144] = (float (*)[144])smem;
  const float sc = 1.0f / 32.0f;   // 2^-5 folded in
  for (int i = tid; i < 64 * 144; i += 320) {
    int c = i / 144, e = i - c * 144;
    int h = e / 12, w = e - h * 12;
    ask[c][e] = (A[c * 144 + e] - A[c * 144 + w * 12 + h]) * sc;
  }

  // ---- dx for my quad's matrix p = t0+q, lane owns c in [16eg,16eg+16) ----
  // (global loads issued before the barrier to hide latency under staging)
  float dxv[16];
  {
    const int p = t0 + q;                       // q<80 -> p<=2063, clamps safe
    const int i1 = min(max(p - 7, 0), T_ - 1);
    const int i2 = min(max(p - 5, 0), T_ - 1);
    const float* xb = x + (size_t)b * T_ * C_;
    const float4* r1 = (const float4*)(xb + (size_t)i1 * C_ + 16 * eg);
    const float4* r2 = (const float4*)(xb + (size_t)i2 * C_ + 16 * eg);
#pragma unroll
    for (int m = 0; m < 4; ++m) {
      float4 v1 = r1[m], v2 = r2[m];
      dxv[4 * m + 0] = v2.x - v1.x;
      dxv[4 * m + 1] = v2.y - v1.y;
      dxv[4 * m + 2] = v2.z - v1.z;
      dxv[4 * m + 3] = v2.w - v1.w;
    }
  }
  __syncthreads();

  // ---- build my 3 rows of scaled M: a = sum_c dx[c] * ask[c][rows] ----
  float a[3][12];
  float* af = &a[0][0];
#pragma unroll
  for (int j = 0; j < 36; ++j) af[j] = 0.f;
  const int e0 = eg * 36;
#define BUILD_BLK(OWNER)                                                 \
  _Pragma("unroll")                                                      \
  for (int cc = 0; cc < 16; ++cc) {                                      \
    float d = qb<OWNER>(dxv[cc]);                                        \
    const float4* ar = (const float4*)&ask[OWNER * 16 + cc][e0];         \
    _Pragma("unroll")                                                    \
    for (int qq = 0; qq < 9; ++qq) {                                     \
      float4 v = ar[qq];                                                 \
      af[qq * 4 + 0] = fmaf(d, v.x, af[qq * 4 + 0]);                     \
      af[qq * 4 + 1] = fmaf(d, v.y, af[qq * 4 + 1]);                     \
      af[qq * 4 + 2] = fmaf(d, v.z, af[qq * 4 + 2]);                     \
      af[qq * 4 + 3] = fmaf(d, v.w, af[qq * 4 + 3]);                     \
    }                                                                    \
  }
  BUILD_BLK(0) BUILD_BLK(1) BUILD_BLK(2) BUILD_BLK(3)
#undef BUILD_BLK
  __syncthreads();   // last ask read done -> smem reusable as eb

  // ---- expm: Paterson-Stockmeyer degree-6 (3 mults) + 5 squarings ----
  float b2[3][12], d3[3][12], pp[3][12];
  qmm(a, a, b2);      // M2
  qmm(b2, a, d3);     // M3
#pragma unroll
  for (int i = 0; i < 3; ++i)
#pragma unroll
    for (int j = 0; j < 12; ++j)
      pp[i][j] = a[i][j] + b2[i][j] * 0.5f + d3[i][j] * (1.0f / 6.0f) +
                 ((j == 3 * eg + i) ? 1.0f : 0.0f);
#pragma unroll
  for (int i = 0; i < 3; ++i)
#pragma unroll
    for (int j = 0; j < 12; ++j)
      a[i][j] = a[i][j] * (1.0f / 24.0f) + b2[i][j] * (1.0f / 120.0f) +
                d3[i][j] * (1.0f / 720.0f);
  qmm(d3, a, b2);     // M3*W = M4/24 + M5/120 + M6/720
#pragma unroll
  for (int i = 0; i < 3; ++i)
#pragma unroll
    for (int j = 0; j < 12; ++j) pp[i][j] += b2[i][j];
  qmm(pp, pp, b2);
  qmm(b2, b2, pp);
  qmm(pp, pp, b2);
  qmm(b2, b2, pp);
  qmm(pp, pp, b2);    // E in b2

  // ---- E -> LDS ----
  float (*eb)[LSTRIDE] = (float (*)[LSTRIDE])smem;
  if (q < NQ_) {
    float* lb = &eb[q][0];
#pragma unroll
    for (int i = 0; i < 3; ++i) {
      const int row = 3 * eg + i;
      *(float4*)(lb + row * 12 + 0) = make_float4(b2[i][0], b2[i][1], b2[i][2],  b2[i][3]);
      *(float4*)(lb + row * 12 + 4) = make_float4(b2[i][4], b2[i][5], b2[i][6],  b2[i][7]);
      *(float4*)(lb + row * 12 + 8) = make_float4(b2[i][8], b2[i][9], b2[i][10], b2[i][11]);
    }
  }
  __syncthreads();

  // ---- chain: quads 0..63 own window t = t0+q ----
  if (q < 64) {
    const int t = t0 + q;
    float z[3][12], c[3][12];
#pragma unroll
    for (int i = 0; i < 3; ++i) {
      const float* zp = &eb[q][(3 * eg + i) * 12];
      float4 v0 = *(const float4*)(zp + 0);
      float4 v1 = *(const float4*)(zp + 4);
      float4 v2 = *(const float4*)(zp + 8);
      z[i][0] = v0.x; z[i][1] = v0.y; z[i][2]  = v0.z; z[i][3]  = v0.w;
      z[i][4] = v1.x; z[i][5] = v1.y; z[i][6]  = v1.z; z[i][7]  = v1.w;
      z[i][8] = v2.x; z[i][9] = v2.y; z[i][10] = v2.z; z[i][11] = v2.w;
    }
    matmul_rows(z, &eb[q + 2][0], c);
    matmul_rows(c, &eb[q + 4][0], z);
    matmul_rows(z, &eb[q + 6][0], c);
    matmul_rows(c, &eb[q + 8][0], z);
    matmul_rows(z, &eb[q + 10][0], c);
    matmul_rows(c, &eb[q + 12][0], z);

    const size_t obase = ((size_t)b * T_ + t) * 208;
#pragma unroll
    for (int i = 0; i < 3; ++i) {
      const int row = 3 * eg + i;
      *(float4*)(out + obase + row * 12 + 0) = make_float4(z[i][0], z[i][1], z[i][2],  z[i][3]);
      *(float4*)(out + obase + row * 12 + 4) = make_float4(z[i][4], z[i][5], z[i][6],  z[i][7]);
      *(float4*)(out + obase + row * 12 + 8) = make_float4(z[i][8], z[i][9], z[i][10], z[i][11]);
    }
    const int xi = min(max(t - 7, 0), T_ - 1);
    const float* xr = x + ((size_t)b * T_ + xi) * C_ + 16 * eg;
#pragma unroll
    for (int m = 0; m < 4; ++m) {
      *(float4*)(out + obase + 144 + 16 * eg + m * 4) = *(const float4*)(xr + m * 4);
    }
  }
}

// ------------------------------------------------------------------
extern "C" void kernel_launch(void* const* d_in, const int* in_sizes, int n_in,
                              void* d_out, int out_size, void* d_ws, size_t ws_size,
                              hipStream_t stream) {
  (void)in_sizes; (void)n_in; (void)out_size; (void)d_ws; (void)ws_size;
  const float* x = (const float*)d_in[0];
  const float* A = (const float*)d_in[1];
  float* out = (float*)d_out;

  fused_kernel<<<dim3(T_ / 64, 32), 320, 0, stream>>>(x, A, out);
}

// Round 5
// 392.904 us; speedup vs baseline: 2.1613x; 2.1613x over previous
//
#include <hip/hip_runtime.h>

#define T_ 2048
#define C_ 64
#define LSTRIDE 148       // padded LDS stride (592 B = 37*16B): chain reads 2-way max
#define NQ_ 76            // matrices per block: p = t0 .. t0+75

// ------------------------------------------------------------------
// Quad-lane DPP broadcast: all 4 lanes of a quad get lane Q's value.
// ------------------------------------------------------------------
template <int Q>
__device__ __forceinline__ float qb(float v) {
  return __int_as_float(
      __builtin_amdgcn_mov_dpp(__float_as_int(v), Q * 0x55, 0xf, 0xf, true));
}

// C(3x12, own rows) = A(3x12, own rows) * B(12x12, quad-distributed rows)
__device__ __forceinline__ void qmm(const float a[3][12], const float b[3][12],
                                    float c[3][12]) {
#pragma unroll
  for (int i = 0; i < 3; ++i)
#pragma unroll
    for (int j = 0; j < 12; ++j) c[i][j] = 0.f;
#define QMM_K(OWNER, E)                                                  \
  {                                                                      \
    float bk[12];                                                        \
    _Pragma("unroll")                                                    \
    for (int j = 0; j < 12; ++j) bk[j] = qb<OWNER>(b[E][j]);             \
    _Pragma("unroll")                                                    \
    for (int i = 0; i < 3; ++i) {                                        \
      const float av = a[i][3 * OWNER + E];                              \
      _Pragma("unroll")                                                  \
      for (int j = 0; j < 12; ++j) c[i][j] = fmaf(av, bk[j], c[i][j]);   \
    }                                                                    \
  }
  QMM_K(0, 0) QMM_K(0, 1) QMM_K(0, 2)
  QMM_K(1, 0) QMM_K(1, 1) QMM_K(1, 2)
  QMM_K(2, 0) QMM_K(2, 1) QMM_K(2, 2)
  QMM_K(3, 0) QMM_K(3, 1) QMM_K(3, 2)
#undef QMM_K
}

// C(3x12, own rows) = A(3x12, own rows) * B(12x12 in LDS, rows contiguous)
// Quad-uniform addresses -> LDS broadcast.
__device__ __forceinline__ void matmul_rows(const float a[3][12],
                                            const float* lb, float c[3][12]) {
#pragma unroll
  for (int i = 0; i < 3; ++i)
#pragma unroll
    for (int j = 0; j < 12; ++j) c[i][j] = 0.f;
#pragma unroll
  for (int k = 0; k < 12; ++k) {
    float4 b0 = *(const float4*)(lb + k * 12 + 0);
    float4 b1 = *(const float4*)(lb + k * 12 + 4);
    float4 b2 = *(const float4*)(lb + k * 12 + 8);
#pragma unroll
    for (int i = 0; i < 3; ++i) {
      const float a_ = a[i][k];
      c[i][0] += a_ * b0.x;  c[i][1] += a_ * b0.y;  c[i][2]  += a_ * b0.z;  c[i][3]  += a_ * b0.w;
      c[i][4] += a_ * b1.x;  c[i][5] += a_ * b1.y;  c[i][6]  += a_ * b1.z;  c[i][7]  += a_ * b1.w;
      c[i][8] += a_ * b2.x;  c[i][9] += a_ * b2.y;  c[i][10] += a_ * b2.z;  c[i][11] += a_ * b2.w;
    }
  }
}

// ------------------------------------------------------------------
// Fully fused: per block = (b, t0..t0+63). Build 76 scaled M's in regs
// (dx in regs via quad-DPP, ask broadcast from LDS), expm in regs
// (PS-6 Taylor + 5 squarings), E -> LDS (union with ask), chain + output.
// 320 threads = 5 waves = 80 quads (76 used for expm, 64 for chain).
// NOTE: no min-waves-per-EU bound — round 4 showed that forcing 3 waves/EU
// caps VGPR at 84 and spills the ~160-float live set (2.4 GB scratch traffic).
// ------------------------------------------------------------------
__global__ __launch_bounds__(320) void fused_kernel(const float* __restrict__ x,
                                                    const float* __restrict__ A,
                                                    float* __restrict__ out) {
  __shared__ float smem[NQ_ * LSTRIDE];   // 44992 B; ask (9216 floats) unions with eb
  const int b = blockIdx.y;
  const int t0 = blockIdx.x * 64;
  const int tid = threadIdx.x;
  const int q = tid >> 2;     // quad 0..79
  const int eg = tid & 3;     // lane in quad: owns rows 3eg..3eg+2

  // ---- stage scaled skew-symmetrized A into LDS ----
  float (*ask)[144] = (float (*)[144])smem;
  const float sc = 1.0f / 32.0f;   // 2^-5 folded in
  for (int i = tid; i < 64 * 144; i += 320) {
    int c = i / 144, e = i - c * 144;
    int h = e / 12, w = e - h * 12;
    ask[c][e] = (A[c * 144 + e] - A[c * 144 + w * 12 + h]) * sc;
  }

  // ---- dx for my quad's matrix p = t0+q, lane owns c in [16eg,16eg+16) ----
  float dxv[16];
  {
    const int p = t0 + q;                       // q<80 -> p<=2063, clamps safe
    const int i1 = min(max(p - 7, 0), T_ - 1);
    const int i2 = min(max(p - 5, 0), T_ - 1);
    const float* xb = x + (size_t)b * T_ * C_;
    const float4* r1 = (const float4*)(xb + (size_t)i1 * C_ + 16 * eg);
    const float4* r2 = (const float4*)(xb + (size_t)i2 * C_ + 16 * eg);
#pragma unroll
    for (int m = 0; m < 4; ++m) {
      float4 v1 = r1[m], v2 = r2[m];
      dxv[4 * m + 0] = v2.x - v1.x;
      dxv[4 * m + 1] = v2.y - v1.y;
      dxv[4 * m + 2] = v2.z - v1.z;
      dxv[4 * m + 3] = v2.w - v1.w;
    }
  }
  __syncthreads();

  // ---- build my 3 rows of scaled M: a = sum_c dx[c] * ask[c][rows] ----
  float a[3][12];
  float* af = &a[0][0];
#pragma unroll
  for (int j = 0; j < 36; ++j) af[j] = 0.f;
  const int e0 = eg * 36;
#define BUILD_BLK(OWNER)                                                 \
  _Pragma("unroll")                                                      \
  for (int cc = 0; cc < 16; ++cc) {                                      \
    float d = qb<OWNER>(dxv[cc]);                                        \
    const float4* ar = (const float4*)&ask[OWNER * 16 + cc][e0];         \
    _Pragma("unroll")                                                    \
    for (int qq = 0; qq < 9; ++qq) {                                     \
      float4 v = ar[qq];                                                 \
      af[qq * 4 + 0] = fmaf(d, v.x, af[qq * 4 + 0]);                     \
      af[qq * 4 + 1] = fmaf(d, v.y, af[qq * 4 + 1]);                     \
      af[qq * 4 + 2] = fmaf(d, v.z, af[qq * 4 + 2]);                     \
      af[qq * 4 + 3] = fmaf(d, v.w, af[qq * 4 + 3]);                     \
    }                                                                    \
  }
  BUILD_BLK(0) BUILD_BLK(1) BUILD_BLK(2) BUILD_BLK(3)
#undef BUILD_BLK
  __syncthreads();   // last ask read done -> smem reusable as eb

  // ---- expm: Paterson-Stockmeyer degree-6 (3 mults) + 5 squarings ----
  float b2[3][12], d3[3][12], pp[3][12];
  qmm(a, a, b2);      // M2
  qmm(b2, a, d3);     // M3
#pragma unroll
  for (int i = 0; i < 3; ++i)
#pragma unroll
    for (int j = 0; j < 12; ++j)
      pp[i][j] = a[i][j] + b2[i][j] * 0.5f + d3[i][j] * (1.0f / 6.0f) +
                 ((j == 3 * eg + i) ? 1.0f : 0.0f);
#pragma unroll
  for (int i = 0; i < 3; ++i)
#pragma unroll
    for (int j = 0; j < 12; ++j)
      a[i][j] = a[i][j] * (1.0f / 24.0f) + b2[i][j] * (1.0f / 120.0f) +
                d3[i][j] * (1.0f / 720.0f);
  qmm(d3, a, b2);     // M3*W = M4/24 + M5/120 + M6/720
#pragma unroll
  for (int i = 0; i < 3; ++i)
#pragma unroll
    for (int j = 0; j < 12; ++j) pp[i][j] += b2[i][j];
  qmm(pp, pp, b2);
  qmm(b2, b2, pp);
  qmm(pp, pp, b2);
  qmm(b2, b2, pp);
  qmm(pp, pp, b2);    // E in b2

  // ---- E -> LDS ----
  float (*eb)[LSTRIDE] = (float (*)[LSTRIDE])smem;
  if (q < NQ_) {
    float* lb = &eb[q][0];
#pragma unroll
    for (int i = 0; i < 3; ++i) {
      const int row = 3 * eg + i;
      *(float4*)(lb + row * 12 + 0) = make_float4(b2[i][0], b2[i][1], b2[i][2],  b2[i][3]);
      *(float4*)(lb + row * 12 + 4) = make_float4(b2[i][4], b2[i][5], b2[i][6],  b2[i][7]);
      *(float4*)(lb + row * 12 + 8) = make_float4(b2[i][8], b2[i][9], b2[i][10], b2[i][11]);
    }
  }
  __syncthreads();

  // ---- chain: quads 0..63 own window t = t0+q ----
  if (q < 64) {
    const int t = t0 + q;
    float z[3][12], c[3][12];
#pragma unroll
    for (int i = 0; i < 3; ++i) {
      const float* zp = &eb[q][(3 * eg + i) * 12];
      float4 v0 = *(const float4*)(zp + 0);
      float4 v1 = *(const float4*)(zp + 4);
      float4 v2 = *(const float4*)(zp + 8);
      z[i][0] = v0.x; z[i][1] = v0.y; z[i][2]  = v0.z; z[i][3]  = v0.w;
      z[i][4] = v1.x; z[i][5] = v1.y; z[i][6]  = v1.z; z[i][7]  = v1.w;
      z[i][8] = v2.x; z[i][9] = v2.y; z[i][10] = v2.z; z[i][11] = v2.w;
    }
    matmul_rows(z, &eb[q + 2][0], c);
    matmul_rows(c, &eb[q + 4][0], z);
    matmul_rows(z, &eb[q + 6][0], c);
    matmul_rows(c, &eb[q + 8][0], z);
    matmul_rows(z, &eb[q + 10][0], c);
    matmul_rows(c, &eb[q + 12][0], z);

    const size_t obase = ((size_t)b * T_ + t) * 208;
#pragma unroll
    for (int i = 0; i < 3; ++i) {
      const int row = 3 * eg + i;
      *(float4*)(out + obase + row * 12 + 0) = make_float4(z[i][0], z[i][1], z[i][2],  z[i][3]);
      *(float4*)(out + obase + row * 12 + 4) = make_float4(z[i][4], z[i][5], z[i][6],  z[i][7]);
      *(float4*)(out + obase + row * 12 + 8) = make_float4(z[i][8], z[i][9], z[i][10], z[i][11]);
    }
    const int xi = min(max(t - 7, 0), T_ - 1);
    const float* xr = x + ((size_t)b * T_ + xi) * C_ + 16 * eg;
#pragma unroll
    for (int m = 0; m < 4; ++m) {
      *(float4*)(out + obase + 144 + 16 * eg + m * 4) = *(const float4*)(xr + m * 4);
    }
  }
}

// ------------------------------------------------------------------
extern "C" void kernel_launch(void* const* d_in, const int* in_sizes, int n_in,
                              void* d_out, int out_size, void* d_ws, size_t ws_size,
                              hipStream_t stream) {
  (void)in_sizes; (void)n_in; (void)out_size; (void)d_ws; (void)ws_size;
  const float* x = (const float*)d_in[0];
  const float* A = (const float*)d_in[1];
  float* out = (float*)d_out;

  fused_kernel<<<dim3(T_ / 64, 32), 320, 0, stream>>>(x, A, out);
}